// Round 5
// baseline (542.967 us; speedup 1.0000x reference)
//
#include <hip/hip_runtime.h>

typedef short short8  __attribute__((ext_vector_type(8)));
typedef short short4v __attribute__((ext_vector_type(4)));
typedef float float4v __attribute__((ext_vector_type(4)));
typedef int   int4v   __attribute__((ext_vector_type(4)));

__device__ __forceinline__ short f2bf(float f) {
    unsigned u = __builtin_bit_cast(unsigned, f);
    u += 0x7fff + ((u >> 16) & 1);   // RNE
    return (short)(u >> 16);
}

__device__ __forceinline__ void gl_lds16(const void* g, void* l) {
    __builtin_amdgcn_global_load_lds(
        (const __attribute__((address_space(1))) void*)g,
        (__attribute__((address_space(3))) void*)l, 16, 0, 0);
}

// ---------------------------------------------------------------------------
// prep: blocks [0,1024): transpose 4 weight matrices [1024,1024] f32 -> bf16
//       blocks [1024,7168): convert q/k/v f32 -> bf16 (8 elems/thread).
// ---------------------------------------------------------------------------
__global__ __launch_bounds__(256) void prep(
    const float* __restrict__ W0, const float* __restrict__ W1,
    const float* __restrict__ W2, const float* __restrict__ W3,
    short* __restrict__ T0, short* __restrict__ T1,
    short* __restrict__ T2, short* __restrict__ T3,
    const float* __restrict__ qf, const float* __restrict__ kf,
    const float* __restrict__ vf,
    short* __restrict__ Qb, short* __restrict__ Kb, short* __restrict__ Vb)
{
    __shared__ short Tl[64 * 72];
    const int tid = threadIdx.x;
    if (blockIdx.x >= 1024) {
        int cid = blockIdx.x - 1024;          // 0..6143
        int arr = cid >> 11;                  // 0..2
        const float* src = arr == 0 ? qf : arr == 1 ? kf : vf;
        short*       dst = arr == 0 ? Qb : arr == 1 ? Kb : Vb;
        size_t base = ((size_t)(cid & 2047) * 256 + tid) * 8;
        float4v v0 = *(const float4v*)&src[base];
        float4v v1 = *(const float4v*)&src[base + 4];
        short8 o = {f2bf(v0[0]), f2bf(v0[1]), f2bf(v0[2]), f2bf(v0[3]),
                    f2bf(v1[0]), f2bf(v1[1]), f2bf(v1[2]), f2bf(v1[3])};
        *(short8*)&dst[base] = o;
        return;
    }
    const int mat = blockIdx.x >> 8;
    const int t   = blockIdx.x & 255;
    const int k0 = (t >> 4) * 64, n0 = (t & 15) * 64;
    const float* W = mat == 0 ? W0 : mat == 1 ? W1 : mat == 2 ? W2 : W3;
    short*       T = mat == 0 ? T0 : mat == 1 ? T1 : mat == 2 ? T2 : T3;
    #pragma unroll
    for (int i = 0; i < 4; i++) {
        int c = tid + i * 256;
        int row = c >> 4, c4 = (c & 15) * 4;
        float4v v = *(const float4v*)&W[(size_t)(k0 + row) * 1024 + n0 + c4];
        short4v s = {f2bf(v[0]), f2bf(v[1]), f2bf(v[2]), f2bf(v[3])};
        *(short4v*)&Tl[row * 72 + c4] = s;
    }
    __syncthreads();
    #pragma unroll
    for (int i = 0; i < 2; i++) {
        int c = tid + i * 256;
        int nrow = c >> 3, k8 = (c & 7) * 8;
        short8 v;
        #pragma unroll
        for (int e = 0; e < 8; e++) v[e] = Tl[(k8 + e) * 72 + nrow];
        *(short8*)&T[(size_t)(n0 + nrow) * 1024 + k0 + k8] = v;
    }
}

// ---------------------------------------------------------------------------
// Shared GEMM body — m97 config: BM=128, BN=128, BK=64, 4 waves (2x2; wave
// tile 64x64, acc[4][4], 32 MFMA / K-step).  global_load_lds width=16 into
// linear LDS, pre-swizzled source, swizzled ds_read_b128 (rule #21).
// ---------------------------------------------------------------------------
__device__ __forceinline__ void gemm_body128(
    const short* __restrict__ A, const short* __restrict__ Bt,
    short* As, short* Bs, float4v (&acc)[4][4], int m0, int n0, int K)
{
    const int tid = threadIdx.x;
    const int w = tid >> 6, lid = tid & 63, quad = lid >> 4, l15 = lid & 15;
    const int wr = w >> 1, wc = w & 1;
    const int lrow = lid >> 3, lcb = lid & 7;

    for (int kb = 0; kb < K; kb += 64) {
        #pragma unroll
        for (int p = 0; p < 4; p++) {
            int chunk = p * 4 + w;
            int row = chunk * 8 + lrow;
            int cb = lcb ^ (row & 7);
            gl_lds16(&A[(size_t)(m0 + row) * K + kb + cb * 8], &As[chunk * 512]);
        }
        #pragma unroll
        for (int p = 0; p < 4; p++) {
            int chunk = p * 4 + w;
            int row = chunk * 8 + lrow;
            int cb = lcb ^ (row & 7);
            gl_lds16(&Bt[(size_t)(n0 + row) * K + kb + cb * 8], &Bs[chunk * 512]);
        }
        __syncthreads();

        short8 af[4][2], bfr[4][2];
        #pragma unroll
        for (int i = 0; i < 4; i++) {
            int row = wr * 64 + i * 16 + l15;
            int sw = row & 7;
            #pragma unroll
            for (int h = 0; h < 2; h++)
                af[i][h] = *(short8*)&As[row * 64 + ((h * 4 + quad) ^ sw) * 8];
        }
        #pragma unroll
        for (int j = 0; j < 4; j++) {
            int row = wc * 64 + j * 16 + l15;
            int sw = row & 7;
            #pragma unroll
            for (int h = 0; h < 2; h++)
                bfr[j][h] = *(short8*)&Bs[row * 64 + ((h * 4 + quad) ^ sw) * 8];
        }
        #pragma unroll
        for (int i = 0; i < 4; i++)
            #pragma unroll
            for (int j = 0; j < 4; j++) {
                acc[i][j] = __builtin_amdgcn_mfma_f32_16x16x32_bf16(
                    af[i][0], bfr[j][0], acc[i][j], 0, 0, 0);
                acc[i][j] = __builtin_amdgcn_mfma_f32_16x16x32_bf16(
                    af[i][1], bfr[j][1], acc[i][j], 0, 0, 0);
            }
        __syncthreads();
    }
}

// ---------------------------------------------------------------------------
// QKV projections in ONE launch: blockIdx.z = 0(Q)/1(K)/2(V).
// z<2: bf16 natural [M][N];  z=2: bf16 transposed-per-batch Vt[b][n][s].
// ---------------------------------------------------------------------------
__global__ __launch_bounds__(256) void gemm_qkv(
    const short* __restrict__ Ab, const short* __restrict__ Btb,
    const float* __restrict__ b0, const float* __restrict__ b1,
    const float* __restrict__ b2, short* __restrict__ Cq,
    short* __restrict__ Ck, short* __restrict__ Cvt)
{
    __shared__ short As[128 * 64];
    __shared__ short Bs[128 * 64];
    const int zz = blockIdx.z;
    const short* A  = Ab  + (size_t)zz * 4194304;
    const short* Bt = Btb + (size_t)zz * 1048576;
    const float* bias = zz == 0 ? b0 : zz == 1 ? b1 : b2;
    const int m0 = blockIdx.x * 128, n0 = blockIdx.y * 128;

    float4v acc[4][4];
    #pragma unroll
    for (int i = 0; i < 4; i++)
        #pragma unroll
        for (int j = 0; j < 4; j++) acc[i][j] = (float4v){0.f, 0.f, 0.f, 0.f};

    gemm_body128(A, Bt, As, Bs, acc, m0, n0, 1024);

    const int tid = threadIdx.x;
    const int w = tid >> 6, lid = tid & 63, quad = lid >> 4, l15 = lid & 15;
    const int wr = w >> 1, wc = w & 1;
    #pragma unroll
    for (int j = 0; j < 4; j++) {
        int n = n0 + wc * 64 + j * 16 + l15;
        float bj = bias[n];
        #pragma unroll
        for (int i = 0; i < 4; i++) {
            if (zz == 2) {
                int b = m0 >> 10;
                int sbase = (m0 & 1023) + wr * 64 + i * 16 + quad * 4;
                short4v sv;
                #pragma unroll
                for (int r = 0; r < 4; r++) sv[r] = f2bf(acc[i][j][r] + bj);
                *(short4v*)&Cvt[(size_t)b * 1048576 + (size_t)n * 1024 + sbase] = sv;
            } else {
                short* C = zz == 0 ? Cq : Ck;
                #pragma unroll
                for (int r = 0; r < 4; r++) {
                    int m = m0 + wr * 64 + i * 16 + quad * 4 + r;
                    C[(size_t)m * 1024 + n] = f2bf(acc[i][j][r] + bj);
                }
            }
        }
    }
}

// ---------------------------------------------------------------------------
// Output projection: A bf16, C f32 natural + bias.
// ---------------------------------------------------------------------------
__global__ __launch_bounds__(256) void gemm_out(
    const short* __restrict__ A, const short* __restrict__ Bt,
    const float* __restrict__ bias, float* __restrict__ C)
{
    __shared__ short As[128 * 64];
    __shared__ short Bs[128 * 64];
    const int m0 = blockIdx.x * 128, n0 = blockIdx.y * 128;
    float4v acc[4][4];
    #pragma unroll
    for (int i = 0; i < 4; i++)
        #pragma unroll
        for (int j = 0; j < 4; j++) acc[i][j] = (float4v){0.f, 0.f, 0.f, 0.f};

    gemm_body128(A, Bt, As, Bs, acc, m0, n0, 1024);

    const int tid = threadIdx.x;
    const int w = tid >> 6, lid = tid & 63, quad = lid >> 4, l15 = lid & 15;
    const int wr = w >> 1, wc = w & 1;
    #pragma unroll
    for (int j = 0; j < 4; j++) {
        int n = n0 + wc * 64 + j * 16 + l15;
        float bj = bias[n];
        #pragma unroll
        for (int i = 0; i < 4; i++)
            #pragma unroll
            for (int r = 0; r < 4; r++) {
                int m = m0 + wr * 64 + i * 16 + quad * 4 + r;
                C[(size_t)m * 1024 + n] = acc[i][j][r] + bj;
            }
    }
}

// ---------------------------------------------------------------------------
// Fused attention v5.  Block = one (b,h) x 16 q-rows, 4 waves split the 1024
// key cols.  S phase: K frags direct from global (L2-resident), no barriers.
// PV phase: per-wave f32 P-transpose in LDS (parity-doubled), A-frag in-reg
// cvt, V frags direct from global — NO stores inside the loop, so PV's vmcnt
// waits never block on store retirement.  All attnOut NT stores replayed
// AFTER the PV loop (P re-derived from still-live accS*inv — same bits).
// ---------------------------------------------------------------------------
__global__ __launch_bounds__(256) void attn_kernel(
    const short* __restrict__ Qp, const short* __restrict__ Kp,
    const short* __restrict__ Vt, const int* __restrict__ mask,
    float* __restrict__ attnOut, short* __restrict__ X)
{
    // SH alias:  P tiles  [2 parity][4 waves][16 q][36 cols] f32 = 4608 f
    //            X reduce [4 waves][16 q][64 d]  f32          = 4096 f
    __shared__ float SH[4608];
    __shared__ int   maskl[1024];
    __shared__ float redmx[4][16];
    __shared__ float redsm[4][16];

    const int tid = threadIdx.x;
    const int w = tid >> 6, lid = tid & 63, quad = lid >> 4, l15 = lid & 15;
    const int bid = blockIdx.x;
    const int qb = bid & 63;
    const int bh = bid >> 6;
    const int b = bh >> 4, h = bh & 15;
    const int q0 = qb * 16;
    const size_t rowbase = (size_t)b * 1048576;
    const size_t hoff = (size_t)h * 64;

    *(int4v*)&maskl[tid * 4] = *(const int4v*)&mask[b * 1024 + tid * 4];

    short8 aq0 = *(const short8*)
        &Qp[rowbase + (size_t)(q0 + l15) * 1024 + hoff + quad * 8];
    short8 aq1 = *(const short8*)
        &Qp[rowbase + (size_t)(q0 + l15) * 1024 + hoff + 32 + quad * 8];

    // ---- S = Q K^T : accS[a] holds cols (a>>1)*128 + w*32 + (a&1)*16 + l15
    float4v accS[16];
    #pragma unroll
    for (int a = 0; a < 16; a++) accS[a] = (float4v){0.f, 0.f, 0.f, 0.f};

    #pragma unroll
    for (int nk = 0; nk < 8; nk++) {
        #pragma unroll
        for (int jj = 0; jj < 2; jj++) {
            int n = nk * 128 + w * 32 + jj * 16 + l15;
            const short* kr = &Kp[rowbase + (size_t)n * 1024 + hoff + quad * 8];
            short8 b0 = *(const short8*)kr;
            short8 b1 = *(const short8*)(kr + 32);
            int a = nk * 2 + jj;
            accS[a] = __builtin_amdgcn_mfma_f32_16x16x32_bf16(aq0, b0, accS[a], 0, 0, 0);
            accS[a] = __builtin_amdgcn_mfma_f32_16x16x32_bf16(aq1, b1, accS[a], 0, 0, 0);
        }
    }
    __syncthreads();   // maskl ready

    // ---- scale + mask + softmax (f32) ----
    float mx[4] = {-3e38f, -3e38f, -3e38f, -3e38f};
    #pragma unroll
    for (int a = 0; a < 16; a++) {
        int col = (a >> 1) * 128 + w * 32 + (a & 1) * 16 + l15;
        bool keep = maskl[col] != 0;
        #pragma unroll
        for (int r = 0; r < 4; r++) {
            float s = accS[a][r] * 0.125f;
            s = keep ? s : -1e10f;
            accS[a][r] = s;
            mx[r] = fmaxf(mx[r], s);
        }
    }
    #pragma unroll
    for (int off = 1; off < 16; off <<= 1)
        #pragma unroll
        for (int r = 0; r < 4; r++) mx[r] = fmaxf(mx[r], __shfl_xor(mx[r], off));
    if (l15 == 0) {
        #pragma unroll
        for (int r = 0; r < 4; r++) redmx[w][quad * 4 + r] = mx[r];
    }
    __syncthreads();
    float mrow[4], sm[4] = {0.f, 0.f, 0.f, 0.f};
    #pragma unroll
    for (int r = 0; r < 4; r++) {
        int qr = quad * 4 + r;
        mrow[r] = fmaxf(fmaxf(redmx[0][qr], redmx[1][qr]),
                        fmaxf(redmx[2][qr], redmx[3][qr]));
    }
    #pragma unroll
    for (int a = 0; a < 16; a++)
        #pragma unroll
        for (int r = 0; r < 4; r++) {
            float e = __expf(accS[a][r] - mrow[r]);
            accS[a][r] = e;
            sm[r] += e;
        }
    #pragma unroll
    for (int off = 1; off < 16; off <<= 1)
        #pragma unroll
        for (int r = 0; r < 4; r++) sm[r] += __shfl_xor(sm[r], off);
    if (l15 == 0) {
        #pragma unroll
        for (int r = 0; r < 4; r++) redsm[w][quad * 4 + r] = sm[r];
    }
    __syncthreads();
    float inv[4];
    #pragma unroll
    for (int r = 0; r < 4; r++) {
        int qr = quad * 4 + r;
        inv[r] = 1.0f / (redsm[0][qr] + redsm[1][qr] + redsm[2][qr] + redsm[3][qr]);
    }

    // ---- PV: wave w owns k-slice w*32..+31 of each 128-tile; no stores ----
    float* Pw0 = &SH[(size_t)(0 * 4 + w) * 16 * 36];
    float* Pw1 = &SH[(size_t)(1 * 4 + w) * 16 * 36];
    float4v accA[4], accB[4];
    #pragma unroll
    for (int jj = 0; jj < 4; jj++) {
        accA[jj] = (float4v){0.f, 0.f, 0.f, 0.f};
        accB[jj] = (float4v){0.f, 0.f, 0.f, 0.f};
    }

    #pragma unroll
    for (int t = 0; t < 4; t++) {
        #pragma unroll
        for (int par = 0; par < 2; par++) {
            int kt = t * 2 + par;
            float* Pw = par ? Pw1 : Pw0;
            float4v* accp = par ? accB : accA;
            #pragma unroll
            for (int jj2 = 0; jj2 < 2; jj2++) {
                int a = kt * 2 + jj2;
                #pragma unroll
                for (int r = 0; r < 4; r++)
                    Pw[(quad * 4 + r) * 36 + jj2 * 16 + l15] = accS[a][r] * inv[r];
            }
            // wave-coherent LDS RAW (lgkmcnt only, no barrier)
            float4v pa0 = *(float4v*)&Pw[l15 * 36 + quad * 8];
            float4v pa1 = *(float4v*)&Pw[l15 * 36 + quad * 8 + 4];
            short8 ap = {f2bf(pa0[0]), f2bf(pa0[1]), f2bf(pa0[2]), f2bf(pa0[3]),
                         f2bf(pa1[0]), f2bf(pa1[1]), f2bf(pa1[2]), f2bf(pa1[3])};
            #pragma unroll
            for (int jj = 0; jj < 4; jj++) {
                short8 bv = *(const short8*)
                    &Vt[rowbase + (hoff + jj * 16 + l15) * 1024 +
                        kt * 128 + w * 32 + quad * 8];
                accp[jj] = __builtin_amdgcn_mfma_f32_16x16x32_bf16(ap, bv, accp[jj], 0, 0, 0);
            }
        }
    }

    // ---- attnOut stores, decoupled from PV (per-wave LDS replay) ----
    const size_t abase = ((size_t)bh * 1024 + q0) * 1024;
    #pragma unroll
    for (int kt = 0; kt < 8; kt++) {
        #pragma unroll
        for (int jj2 = 0; jj2 < 2; jj2++) {
            int a = kt * 2 + jj2;
            #pragma unroll
            for (int r = 0; r < 4; r++)
                Pw0[(quad * 4 + r) * 36 + jj2 * 16 + l15] = accS[a][r] * inv[r];
        }
        #pragma unroll
        for (int pass = 0; pass < 2; pass++) {
            int row = pass * 8 + (lid >> 3), c4 = (lid & 7) * 4;
            float4v pv = *(float4v*)&Pw0[row * 36 + c4];
            __builtin_nontemporal_store(pv, (float4v*)
                &attnOut[abase + (size_t)row * 1024 + kt * 128 + w * 32 + c4]);
        }
    }

    // ---- cross-wave X reduction (SH aliased; barrier separates uses) ----
    __syncthreads();
    float* Xr = SH;   // [4][16][64]
    #pragma unroll
    for (int jj = 0; jj < 4; jj++)
        #pragma unroll
        for (int r = 0; r < 4; r++)
            Xr[(size_t)(w * 16 + quad * 4 + r) * 64 + jj * 16 + l15] =
                accA[jj][r] + accB[jj][r];
    __syncthreads();
    {
        int q = tid >> 4, d4 = (tid & 15) * 4;
        float4v s0 = *(float4v*)&Xr[(size_t)(0 * 16 + q) * 64 + d4];
        float4v s1 = *(float4v*)&Xr[(size_t)(1 * 16 + q) * 64 + d4];
        float4v s2 = *(float4v*)&Xr[(size_t)(2 * 16 + q) * 64 + d4];
        float4v s3 = *(float4v*)&Xr[(size_t)(3 * 16 + q) * 64 + d4];
        short4v o;
        #pragma unroll
        for (int e = 0; e < 4; e++)
            o[e] = f2bf(s0[e] + s1[e] + s2[e] + s3[e]);
        *(short4v*)&X[rowbase + (size_t)(q0 + q) * 1024 + hoff + d4] = o;
    }
}

// ---------------------------------------------------------------------------
extern "C" void kernel_launch(void* const* d_in, const int* in_sizes, int n_in,
                              void* d_out, int out_size, void* d_ws, size_t ws_size,
                              hipStream_t stream)
{
    const float* q_in = (const float*)d_in[0];
    const float* k_in = (const float*)d_in[1];
    const float* v_in = (const float*)d_in[2];
    const int*   mask = (const int*)d_in[3];
    const float* Wq = (const float*)d_in[4];
    const float* bq = (const float*)d_in[5];
    const float* Wk = (const float*)d_in[6];
    const float* bk = (const float*)d_in[7];
    const float* Wv = (const float*)d_in[8];
    const float* bv = (const float*)d_in[9];
    const float* Wo = (const float*)d_in[10];
    const float* bo = (const float*)d_in[11];

    short* ws = (short*)d_ws;
    const size_t MEL = 4096ull * 1024;
    short* Qp  = ws;
    short* Kp  = ws + MEL;
    short* Vt  = ws + 2 * MEL;             // transposed-per-batch V [4][1024][1024]
    short* Xp  = ws + 3 * MEL;
    short* WqT = ws + 4 * MEL;             // WqT/WkT/WvT/WoT contiguous
    short* WkT = WqT + 1024 * 1024;
    short* WvT = WkT + 1024 * 1024;
    short* WoT = WvT + 1024 * 1024;

    float* outp  = (float*)d_out;          // outputs [B,S,D] f32
    float* attnp = outp + MEL;             // attention [B,H,S,S] f32

    // bf16 copies of q/k/v: scratch inside the attention output region
    // (24 MB of 256 MB; fully overwritten by attn_kernel afterwards).
    short* Qb = (short*)attnp;
    short* Kb = Qb + MEL;
    short* Vb = Kb + MEL;

    prep<<<dim3(7168), dim3(256), 0, stream>>>(Wq, Wk, Wv, Wo,
                                               WqT, WkT, WvT, WoT,
                                               q_in, k_in, v_in, Qb, Kb, Vb);
    gemm_qkv<<<dim3(32, 8, 3), 256, 0, stream>>>(Qb, WqT, bq, bk, bv,
                                                 Qp, Kp, Vt);
    attn_kernel<<<dim3(4096), dim3(256), 0, stream>>>(Qp, Kp, Vt, mask, attnp, Xp);
    gemm_out<<<dim3(32, 8), 256, 0, stream>>>(Xp, WoT, bo, outp);
}

// Round 6
// 497.633 us; speedup vs baseline: 1.0911x; 1.0911x over previous
//
#include <hip/hip_runtime.h>

typedef short short8  __attribute__((ext_vector_type(8)));
typedef short short4v __attribute__((ext_vector_type(4)));
typedef float float4v __attribute__((ext_vector_type(4)));
typedef int   int4v   __attribute__((ext_vector_type(4)));

__device__ __forceinline__ short f2bf(float f) {
    unsigned u = __builtin_bit_cast(unsigned, f);
    u += 0x7fff + ((u >> 16) & 1);   // RNE
    return (short)(u >> 16);
}

__device__ __forceinline__ void gl_lds16(const void* g, void* l) {
    __builtin_amdgcn_global_load_lds(
        (const __attribute__((address_space(1))) void*)g,
        (__attribute__((address_space(3))) void*)l, 16, 0, 0);
}

// ---------------------------------------------------------------------------
// prep: blocks [0,1024): transpose 4 weight matrices [1024,1024] f32 -> bf16
//       blocks [1024,7168): convert q/k/v f32 -> bf16 (8 elems/thread).
// ---------------------------------------------------------------------------
__global__ __launch_bounds__(256) void prep(
    const float* __restrict__ W0, const float* __restrict__ W1,
    const float* __restrict__ W2, const float* __restrict__ W3,
    short* __restrict__ T0, short* __restrict__ T1,
    short* __restrict__ T2, short* __restrict__ T3,
    const float* __restrict__ qf, const float* __restrict__ kf,
    const float* __restrict__ vf,
    short* __restrict__ Qb, short* __restrict__ Kb, short* __restrict__ Vb)
{
    __shared__ short Tl[64 * 72];
    const int tid = threadIdx.x;
    if (blockIdx.x >= 1024) {
        int cid = blockIdx.x - 1024;          // 0..6143
        int arr = cid >> 11;                  // 0..2
        const float* src = arr == 0 ? qf : arr == 1 ? kf : vf;
        short*       dst = arr == 0 ? Qb : arr == 1 ? Kb : Vb;
        size_t base = ((size_t)(cid & 2047) * 256 + tid) * 8;
        float4v v0 = *(const float4v*)&src[base];
        float4v v1 = *(const float4v*)&src[base + 4];
        short8 o = {f2bf(v0[0]), f2bf(v0[1]), f2bf(v0[2]), f2bf(v0[3]),
                    f2bf(v1[0]), f2bf(v1[1]), f2bf(v1[2]), f2bf(v1[3])};
        *(short8*)&dst[base] = o;
        return;
    }
    const int mat = blockIdx.x >> 8;
    const int t   = blockIdx.x & 255;
    const int k0 = (t >> 4) * 64, n0 = (t & 15) * 64;
    const float* W = mat == 0 ? W0 : mat == 1 ? W1 : mat == 2 ? W2 : W3;
    short*       T = mat == 0 ? T0 : mat == 1 ? T1 : mat == 2 ? T2 : T3;
    #pragma unroll
    for (int i = 0; i < 4; i++) {
        int c = tid + i * 256;
        int row = c >> 4, c4 = (c & 15) * 4;
        float4v v = *(const float4v*)&W[(size_t)(k0 + row) * 1024 + n0 + c4];
        short4v s = {f2bf(v[0]), f2bf(v[1]), f2bf(v[2]), f2bf(v[3])};
        *(short4v*)&Tl[row * 72 + c4] = s;
    }
    __syncthreads();
    #pragma unroll
    for (int i = 0; i < 2; i++) {
        int c = tid + i * 256;
        int nrow = c >> 3, k8 = (c & 7) * 8;
        short8 v;
        #pragma unroll
        for (int e = 0; e < 8; e++) v[e] = Tl[(k8 + e) * 72 + nrow];
        *(short8*)&T[(size_t)(n0 + nrow) * 1024 + k0 + k8] = v;
    }
}

// ---------------------------------------------------------------------------
// Shared GEMM body — BM=128, BN=64, BK=64, 4 waves (2x2; wave tile 64x32,
// acc[4][2]).  512 blocks/GEMM = 2/CU co-residency (R5 showed BN=128's
// 1 block/CU loses ~28 µs to unoverlapped barrier drains at this N).
// global_load_lds width=16, linear LDS, pre-swizzled source (rule #21).
// ---------------------------------------------------------------------------
__device__ __forceinline__ void gemm_body(
    const short* __restrict__ A, const short* __restrict__ Bt,
    short* As, short* Bs, float4v (&acc)[4][2], int m0, int n0, int K)
{
    const int tid = threadIdx.x;
    const int w = tid >> 6, lid = tid & 63, quad = lid >> 4, l15 = lid & 15;
    const int wr = w >> 1, wc = w & 1;
    const int lrow = lid >> 3, lcb = lid & 7;

    for (int kb = 0; kb < K; kb += 64) {
        #pragma unroll
        for (int p = 0; p < 4; p++) {
            int chunk = p * 4 + w;
            int row = chunk * 8 + lrow;
            int cb = lcb ^ (row & 7);
            gl_lds16(&A[(size_t)(m0 + row) * K + kb + cb * 8], &As[chunk * 512]);
        }
        #pragma unroll
        for (int p = 0; p < 2; p++) {
            int chunk = p * 4 + w;
            int row = chunk * 8 + lrow;
            int cb = lcb ^ (row & 7);
            gl_lds16(&Bt[(size_t)(n0 + row) * K + kb + cb * 8], &Bs[chunk * 512]);
        }
        __syncthreads();

        short8 af[4][2], bfr[2][2];
        #pragma unroll
        for (int i = 0; i < 4; i++) {
            int row = wr * 64 + i * 16 + l15;
            int sw = row & 7;
            #pragma unroll
            for (int h = 0; h < 2; h++)
                af[i][h] = *(short8*)&As[row * 64 + ((h * 4 + quad) ^ sw) * 8];
        }
        #pragma unroll
        for (int j = 0; j < 2; j++) {
            int row = wc * 32 + j * 16 + l15;
            int sw = row & 7;
            #pragma unroll
            for (int h = 0; h < 2; h++)
                bfr[j][h] = *(short8*)&Bs[row * 64 + ((h * 4 + quad) ^ sw) * 8];
        }
        #pragma unroll
        for (int i = 0; i < 4; i++)
            #pragma unroll
            for (int j = 0; j < 2; j++) {
                acc[i][j] = __builtin_amdgcn_mfma_f32_16x16x32_bf16(
                    af[i][0], bfr[j][0], acc[i][j], 0, 0, 0);
                acc[i][j] = __builtin_amdgcn_mfma_f32_16x16x32_bf16(
                    af[i][1], bfr[j][1], acc[i][j], 0, 0, 0);
            }
        __syncthreads();
    }
}

// ---------------------------------------------------------------------------
// QKV projections in ONE launch: blockIdx.z = 0(Q)/1(K)/2(V).
// z<2: bf16 natural [M][N];  z=2: bf16 transposed-per-batch Vt[b][n][s].
// ---------------------------------------------------------------------------
__global__ __launch_bounds__(256) void gemm_qkv(
    const short* __restrict__ Ab, const short* __restrict__ Btb,
    const float* __restrict__ b0, const float* __restrict__ b1,
    const float* __restrict__ b2, short* __restrict__ Cq,
    short* __restrict__ Ck, short* __restrict__ Cvt)
{
    __shared__ short As[128 * 64];
    __shared__ short Bs[64 * 64];
    const int zz = blockIdx.z;
    const short* A  = Ab  + (size_t)zz * 4194304;
    const short* Bt = Btb + (size_t)zz * 1048576;
    const float* bias = zz == 0 ? b0 : zz == 1 ? b1 : b2;
    const int m0 = blockIdx.x * 128, n0 = blockIdx.y * 64;

    float4v acc[4][2];
    #pragma unroll
    for (int i = 0; i < 4; i++)
        #pragma unroll
        for (int j = 0; j < 2; j++) acc[i][j] = (float4v){0.f, 0.f, 0.f, 0.f};

    gemm_body(A, Bt, As, Bs, acc, m0, n0, 1024);

    const int tid = threadIdx.x;
    const int w = tid >> 6, lid = tid & 63, quad = lid >> 4, l15 = lid & 15;
    const int wr = w >> 1, wc = w & 1;
    #pragma unroll
    for (int j = 0; j < 2; j++) {
        int n = n0 + wc * 32 + j * 16 + l15;
        float bj = bias[n];
        #pragma unroll
        for (int i = 0; i < 4; i++) {
            if (zz == 2) {
                int b = m0 >> 10;
                int sbase = (m0 & 1023) + wr * 64 + i * 16 + quad * 4;
                short4v sv;
                #pragma unroll
                for (int r = 0; r < 4; r++) sv[r] = f2bf(acc[i][j][r] + bj);
                *(short4v*)&Cvt[(size_t)b * 1048576 + (size_t)n * 1024 + sbase] = sv;
            } else {
                short* C = zz == 0 ? Cq : Ck;
                #pragma unroll
                for (int r = 0; r < 4; r++) {
                    int m = m0 + wr * 64 + i * 16 + quad * 4 + r;
                    C[(size_t)m * 1024 + n] = f2bf(acc[i][j][r] + bj);
                }
            }
        }
    }
}

// ---------------------------------------------------------------------------
// Output projection: A bf16, C f32 natural + bias.
// ---------------------------------------------------------------------------
__global__ __launch_bounds__(256) void gemm_out(
    const short* __restrict__ A, const short* __restrict__ Bt,
    const float* __restrict__ bias, float* __restrict__ C)
{
    __shared__ short As[128 * 64];
    __shared__ short Bs[64 * 64];
    const int m0 = blockIdx.x * 128, n0 = blockIdx.y * 64;
    float4v acc[4][2];
    #pragma unroll
    for (int i = 0; i < 4; i++)
        #pragma unroll
        for (int j = 0; j < 2; j++) acc[i][j] = (float4v){0.f, 0.f, 0.f, 0.f};

    gemm_body(A, Bt, As, Bs, acc, m0, n0, 1024);

    const int tid = threadIdx.x;
    const int w = tid >> 6, lid = tid & 63, quad = lid >> 4, l15 = lid & 15;
    const int wr = w >> 1, wc = w & 1;
    #pragma unroll
    for (int j = 0; j < 2; j++) {
        int n = n0 + wc * 32 + j * 16 + l15;
        float bj = bias[n];
        #pragma unroll
        for (int i = 0; i < 4; i++)
            #pragma unroll
            for (int r = 0; r < 4; r++) {
                int m = m0 + wr * 64 + i * 16 + quad * 4 + r;
                C[(size_t)m * 1024 + n] = acc[i][j][r] + bj;
            }
    }
}

// ---------------------------------------------------------------------------
// Fused attention v6 = R4 structure (in-loop NT stores) + explicit register
// prefetch.  S phase: K frags double-buffered 2 nk-tiles ahead (kb[2][4]).
// PV phase: V frags double-buffered 1 kt ahead (vb[2][4]), issued FIRST in
// the loop body so their vmcnt retires ahead of the NT stores.
// ---------------------------------------------------------------------------
__global__ __launch_bounds__(256) void attn_kernel(
    const short* __restrict__ Qp, const short* __restrict__ Kp,
    const short* __restrict__ Vt, const int* __restrict__ mask,
    float* __restrict__ attnOut, short* __restrict__ X)
{
    // SH alias:  P tiles  [2 parity][4 waves][16 q][36 cols] f32 = 4608 f
    //            X reduce [4 waves][16 q][64 d]  f32          = 4096 f
    __shared__ float SH[4608];
    __shared__ int   maskl[1024];
    __shared__ float redmx[4][16];
    __shared__ float redsm[4][16];

    const int tid = threadIdx.x;
    const int w = tid >> 6, lid = tid & 63, quad = lid >> 4, l15 = lid & 15;
    const int bid = blockIdx.x;
    const int qb = bid & 63;
    const int bh = bid >> 6;
    const int b = bh >> 4, h = bh & 15;
    const int q0 = qb * 16;
    const size_t rowbase = (size_t)b * 1048576;
    const size_t hoff = (size_t)h * 64;

    *(int4v*)&maskl[tid * 4] = *(const int4v*)&mask[b * 1024 + tid * 4];

    short8 aq0 = *(const short8*)
        &Qp[rowbase + (size_t)(q0 + l15) * 1024 + hoff + quad * 8];
    short8 aq1 = *(const short8*)
        &Qp[rowbase + (size_t)(q0 + l15) * 1024 + hoff + 32 + quad * 8];

    // ---- S = Q K^T : accS[a] holds cols (a>>1)*128 + w*32 + (a&1)*16 + l15
    float4v accS[16];
    #pragma unroll
    for (int a = 0; a < 16; a++) accS[a] = (float4v){0.f, 0.f, 0.f, 0.f};

    // K register double-buffer, 2 nk-tiles ahead
    short8 kb[2][4];
    #pragma unroll
    for (int pb = 0; pb < 2; pb++)
        #pragma unroll
        for (int jj = 0; jj < 2; jj++) {
            int n = pb * 128 + w * 32 + jj * 16 + l15;
            const short* kr = &Kp[rowbase + (size_t)n * 1024 + hoff + quad * 8];
            kb[pb][jj * 2]     = *(const short8*)kr;
            kb[pb][jj * 2 + 1] = *(const short8*)(kr + 32);
        }

    #pragma unroll
    for (int nk = 0; nk < 8; nk++) {
        short8* cur = kb[nk & 1];
        #pragma unroll
        for (int jj = 0; jj < 2; jj++) {
            int a = nk * 2 + jj;
            accS[a] = __builtin_amdgcn_mfma_f32_16x16x32_bf16(
                aq0, cur[jj * 2], accS[a], 0, 0, 0);
            accS[a] = __builtin_amdgcn_mfma_f32_16x16x32_bf16(
                aq1, cur[jj * 2 + 1], accS[a], 0, 0, 0);
        }
        if (nk + 2 < 8) {
            #pragma unroll
            for (int jj = 0; jj < 2; jj++) {
                int n = (nk + 2) * 128 + w * 32 + jj * 16 + l15;
                const short* kr = &Kp[rowbase + (size_t)n * 1024 + hoff + quad * 8];
                cur[jj * 2]     = *(const short8*)kr;
                cur[jj * 2 + 1] = *(const short8*)(kr + 32);
            }
        }
    }
    __syncthreads();   // maskl ready

    // ---- scale + mask + softmax (f32) ----
    float mx[4] = {-3e38f, -3e38f, -3e38f, -3e38f};
    #pragma unroll
    for (int a = 0; a < 16; a++) {
        int col = (a >> 1) * 128 + w * 32 + (a & 1) * 16 + l15;
        bool keep = maskl[col] != 0;
        #pragma unroll
        for (int r = 0; r < 4; r++) {
            float s = accS[a][r] * 0.125f;
            s = keep ? s : -1e10f;
            accS[a][r] = s;
            mx[r] = fmaxf(mx[r], s);
        }
    }
    #pragma unroll
    for (int off = 1; off < 16; off <<= 1)
        #pragma unroll
        for (int r = 0; r < 4; r++) mx[r] = fmaxf(mx[r], __shfl_xor(mx[r], off));
    if (l15 == 0) {
        #pragma unroll
        for (int r = 0; r < 4; r++) redmx[w][quad * 4 + r] = mx[r];
    }
    __syncthreads();
    float mrow[4], sm[4] = {0.f, 0.f, 0.f, 0.f};
    #pragma unroll
    for (int r = 0; r < 4; r++) {
        int qr = quad * 4 + r;
        mrow[r] = fmaxf(fmaxf(redmx[0][qr], redmx[1][qr]),
                        fmaxf(redmx[2][qr], redmx[3][qr]));
    }
    #pragma unroll
    for (int a = 0; a < 16; a++)
        #pragma unroll
        for (int r = 0; r < 4; r++) {
            float e = __expf(accS[a][r] - mrow[r]);
            accS[a][r] = e;
            sm[r] += e;
        }
    #pragma unroll
    for (int off = 1; off < 16; off <<= 1)
        #pragma unroll
        for (int r = 0; r < 4; r++) sm[r] += __shfl_xor(sm[r], off);
    if (l15 == 0) {
        #pragma unroll
        for (int r = 0; r < 4; r++) redsm[w][quad * 4 + r] = sm[r];
    }
    __syncthreads();
    float inv[4];
    #pragma unroll
    for (int r = 0; r < 4; r++) {
        int qr = quad * 4 + r;
        inv[r] = 1.0f / (redsm[0][qr] + redsm[1][qr] + redsm[2][qr] + redsm[3][qr]);
    }

    // ---- PV: wave w owns k-slice w*32..+31 of each 128-tile ----
    const size_t abase = ((size_t)bh * 1024 + q0) * 1024;
    float* Pw0 = &SH[(size_t)(0 * 4 + w) * 16 * 36];
    float* Pw1 = &SH[(size_t)(1 * 4 + w) * 16 * 36];
    float4v accA[4], accB[4];
    #pragma unroll
    for (int jj = 0; jj < 4; jj++) {
        accA[jj] = (float4v){0.f, 0.f, 0.f, 0.f};
        accB[jj] = (float4v){0.f, 0.f, 0.f, 0.f};
    }

    // V register double-buffer, 1 kt ahead
    short8 vb[2][4];
    #pragma unroll
    for (int jj = 0; jj < 4; jj++)
        vb[0][jj] = *(const short8*)
            &Vt[rowbase + (hoff + jj * 16 + l15) * 1024 + w * 32 + quad * 8];

    #pragma unroll
    for (int kt = 0; kt < 8; kt++) {
        int par = kt & 1;
        float* Pw = par ? Pw1 : Pw0;
        float4v* accp = par ? accB : accA;
        // prefetch V for kt+1 FIRST (vmcnt retires before the NT stores)
        if (kt + 1 < 8) {
            #pragma unroll
            for (int jj = 0; jj < 4; jj++)
                vb[(kt + 1) & 1][jj] = *(const short8*)
                    &Vt[rowbase + (hoff + jj * 16 + l15) * 1024 +
                        (kt + 1) * 128 + w * 32 + quad * 8];
        }
        // P values -> per-wave f32 LDS tile (transposed)
        #pragma unroll
        for (int jj2 = 0; jj2 < 2; jj2++) {
            int a = kt * 2 + jj2;
            #pragma unroll
            for (int r = 0; r < 4; r++)
                Pw[(quad * 4 + r) * 36 + jj2 * 16 + l15] = accS[a][r] * inv[r];
        }
        // attnOut: 2 x float4 nontemporal stores (128B row segments)
        #pragma unroll
        for (int pass = 0; pass < 2; pass++) {
            int row = pass * 8 + (lid >> 3), c4 = (lid & 7) * 4;
            float4v pv = *(float4v*)&Pw[row * 36 + c4];
            __builtin_nontemporal_store(pv, (float4v*)
                &attnOut[abase + (size_t)row * 1024 + kt * 128 + w * 32 + c4]);
        }
        // A-frag for PV from the f32 tile (8 cvt in-reg)
        float4v pa0 = *(float4v*)&Pw[l15 * 36 + quad * 8];
        float4v pa1 = *(float4v*)&Pw[l15 * 36 + quad * 8 + 4];
        short8 ap = {f2bf(pa0[0]), f2bf(pa0[1]), f2bf(pa0[2]), f2bf(pa0[3]),
                     f2bf(pa1[0]), f2bf(pa1[1]), f2bf(pa1[2]), f2bf(pa1[3])};
        #pragma unroll
        for (int jj = 0; jj < 4; jj++)
            accp[jj] = __builtin_amdgcn_mfma_f32_16x16x32_bf16(
                ap, vb[par][jj], accp[jj], 0, 0, 0);
    }

    // ---- cross-wave X reduction (SH aliased; barrier separates uses) ----
    __syncthreads();
    float* Xr = SH;   // [4][16][64]
    #pragma unroll
    for (int jj = 0; jj < 4; jj++)
        #pragma unroll
        for (int r = 0; r < 4; r++)
            Xr[(size_t)(w * 16 + quad * 4 + r) * 64 + jj * 16 + l15] =
                accA[jj][r] + accB[jj][r];
    __syncthreads();
    {
        int q = tid >> 4, d4 = (tid & 15) * 4;
        float4v s0 = *(float4v*)&Xr[(size_t)(0 * 16 + q) * 64 + d4];
        float4v s1 = *(float4v*)&Xr[(size_t)(1 * 16 + q) * 64 + d4];
        float4v s2 = *(float4v*)&Xr[(size_t)(2 * 16 + q) * 64 + d4];
        float4v s3 = *(float4v*)&Xr[(size_t)(3 * 16 + q) * 64 + d4];
        short4v o;
        #pragma unroll
        for (int e = 0; e < 4; e++)
            o[e] = f2bf(s0[e] + s1[e] + s2[e] + s3[e]);
        *(short4v*)&X[rowbase + (size_t)(q0 + q) * 1024 + hoff + d4] = o;
    }
}

// ---------------------------------------------------------------------------
extern "C" void kernel_launch(void* const* d_in, const int* in_sizes, int n_in,
                              void* d_out, int out_size, void* d_ws, size_t ws_size,
                              hipStream_t stream)
{
    const float* q_in = (const float*)d_in[0];
    const float* k_in = (const float*)d_in[1];
    const float* v_in = (const float*)d_in[2];
    const int*   mask = (const int*)d_in[3];
    const float* Wq = (const float*)d_in[4];
    const float* bq = (const float*)d_in[5];
    const float* Wk = (const float*)d_in[6];
    const float* bk = (const float*)d_in[7];
    const float* Wv = (const float*)d_in[8];
    const float* bv = (const float*)d_in[9];
    const float* Wo = (const float*)d_in[10];
    const float* bo = (const float*)d_in[11];

    short* ws = (short*)d_ws;
    const size_t MEL = 4096ull * 1024;
    short* Qp  = ws;
    short* Kp  = ws + MEL;
    short* Vt  = ws + 2 * MEL;             // transposed-per-batch V [4][1024][1024]
    short* Xp  = ws + 3 * MEL;
    short* WqT = ws + 4 * MEL;             // WqT/WkT/WvT/WoT contiguous
    short* WkT = WqT + 1024 * 1024;
    short* WvT = WkT + 1024 * 1024;
    short* WoT = WvT + 1024 * 1024;

    float* outp  = (float*)d_out;          // outputs [B,S,D] f32
    float* attnp = outp + MEL;             // attention [B,H,S,S] f32

    // bf16 copies of q/k/v: scratch inside the attention output region
    // (24 MB of 256 MB; fully overwritten by attn_kernel afterwards).
    short* Qb = (short*)attnp;
    short* Kb = Qb + MEL;
    short* Vb = Kb + MEL;

    prep<<<dim3(7168), dim3(256), 0, stream>>>(Wq, Wk, Wv, Wo,
                                               WqT, WkT, WvT, WoT,
                                               q_in, k_in, v_in, Qb, Kb, Vb);
    gemm_qkv<<<dim3(32, 16, 3), 256, 0, stream>>>(Qb, WqT, bq, bk, bv,
                                                  Qp, Kp, Vt);
    attn_kernel<<<dim3(4096), dim3(256), 0, stream>>>(Qp, Kp, Vt, mask, attnp, Xp);
    gemm_out<<<dim3(32, 16), 256, 0, stream>>>(Xp, WoT, bo, outp);
}